// Round 1
// baseline (2146.677 us; speedup 1.0000x reference)
//
#include <hip/hip_runtime.h>
#include <math.h>

#define T_TOK 2048
#define H_DIM 1024
#define M_DIM 512
#define E_NUM 32
#define TOPK  4

#define BT 64
#define BM 64
#define BH 64
#define BK 32

// ---------------- K1: gating (logits -> top4 -> softmax weights) -------------
__global__ __launch_bounds__(256) void gating_kernel(
    const float* __restrict__ x, const float* __restrict__ gate_w,
    int* __restrict__ topk_ids, float* __restrict__ topk_w) {
  __shared__ float xr[H_DIM];
  __shared__ float logits[E_NUM];
  int t = blockIdx.x;
  int tid = threadIdx.x;
  const float* xrow = x + (size_t)t * H_DIM;
  // load the token's row (1024 f32) into LDS
  {
    int i = tid * 4;  // 256 threads * 4 = 1024
    float4 v = *(const float4*)(xrow + i);
    *(float4*)(xr + i) = v;
  }
  __syncthreads();
  int wave = tid >> 6, lane = tid & 63;
  // each wave handles 8 experts; 64-lane strided dot + shuffle reduce
  for (int e8 = 0; e8 < 8; ++e8) {
    int e = wave * 8 + e8;
    const float* gw = gate_w + (size_t)e * H_DIM;
    float p = 0.f;
    for (int i = lane; i < H_DIM; i += 64) p = fmaf(xr[i], gw[i], p);
    for (int off = 32; off > 0; off >>= 1) p += __shfl_down(p, off, 64);
    if (lane == 0) logits[e] = p;
  }
  __syncthreads();
  if (tid == 0) {
    float v[E_NUM];
    for (int e = 0; e < E_NUM; ++e) v[e] = logits[e];
    int ids[TOPK]; float vals[TOPK];
    for (int k = 0; k < TOPK; ++k) {
      int bi = 0; float bv = -1e30f;
      for (int e = 0; e < E_NUM; ++e) if (v[e] > bv) { bv = v[e]; bi = e; }
      ids[k] = bi; vals[k] = bv; v[bi] = -1e30f;
    }
    float m = vals[0];  // sorted descending
    float w[TOPK]; float s = 0.f;
    for (int k = 0; k < TOPK; ++k) { w[k] = expf(vals[k] - m); s += w[k]; }
    float inv = 1.f / s;
    for (int k = 0; k < TOPK; ++k) {
      topk_ids[t * TOPK + k] = ids[k];
      topk_w[t * TOPK + k]   = w[k] * inv;
    }
  }
}

// ---------------- K2: scatter assignments into per-expert lists --------------
__global__ __launch_bounds__(256) void scatter_kernel(
    const int* __restrict__ topk_ids, int* __restrict__ cursors,
    int* __restrict__ tok_list) {
  int g = blockIdx.x * 256 + threadIdx.x;  // assignment id = t*4 + k
  if (g >= T_TOK * TOPK) return;
  int e = topk_ids[g];
  int slot = atomicAdd(&cursors[e], 1);
  tok_list[e * T_TOK + slot] = g;
}

// ---------------- K3: per-expert gate/up GEMM + silu*up*routew -> mixed ------
__global__ __launch_bounds__(256) void gateup_kernel(
    const float* __restrict__ x, const float* __restrict__ w_gate,
    const float* __restrict__ w_up, const float* __restrict__ topk_w,
    const int* __restrict__ cursors, const int* __restrict__ tok_list,
    float* __restrict__ mixed) {
  int e = blockIdx.z;
  int tile = blockIdx.x;
  int cnt = cursors[e];
  if (tile * BT >= cnt) return;
  int m0 = blockIdx.y * BM;

  __shared__ float xs[BK][BT];
  __shared__ float gs[BK][BM];
  __shared__ float us[BK][BM];
  __shared__ int   ent[BT];
  __shared__ float rw[BT];

  int tid = threadIdx.x;
  if (tid < BT) {
    int idx = tile * BT + tid;
    int en = (idx < cnt) ? tok_list[e * T_TOK + idx] : -1;
    ent[tid] = en;
    rw[tid]  = (en >= 0) ? topk_w[en] : 0.f;
  }
  __syncthreads();

  const float* wg = w_gate + (size_t)e * M_DIM * H_DIM;
  const float* wu = w_up   + (size_t)e * M_DIM * H_DIM;

  int lr = tid >> 2;           // 0..63 (row this thread loads)
  int lc = (tid & 3) * 8;      // 0,8,16,24 (col offset, 8 floats)
  int en_r = ent[lr];
  bool valid_r = (en_r >= 0);
  const float* xrow  = x  + (size_t)(valid_r ? (en_r >> 2) : 0) * H_DIM;
  const float* wgrow = wg + (size_t)(m0 + lr) * H_DIM;
  const float* wurow = wu + (size_t)(m0 + lr) * H_DIM;

  int tx = tid & 15, ty = tid >> 4;
  float accg[4][4] = {{0}}; float accu[4][4] = {{0}};

  for (int k0 = 0; k0 < H_DIM; k0 += BK) {
    float va[8], vg[8], vu[8];
    if (valid_r) {
      *(float4*)(va)     = *(const float4*)(xrow + k0 + lc);
      *(float4*)(va + 4) = *(const float4*)(xrow + k0 + lc + 4);
    } else {
      #pragma unroll
      for (int j = 0; j < 8; ++j) va[j] = 0.f;
    }
    *(float4*)(vg)     = *(const float4*)(wgrow + k0 + lc);
    *(float4*)(vg + 4) = *(const float4*)(wgrow + k0 + lc + 4);
    *(float4*)(vu)     = *(const float4*)(wurow + k0 + lc);
    *(float4*)(vu + 4) = *(const float4*)(wurow + k0 + lc + 4);
    __syncthreads();  // previous chunk's compute done
    #pragma unroll
    for (int j = 0; j < 8; ++j) {
      xs[lc + j][lr] = va[j];
      gs[lc + j][lr] = vg[j];
      us[lc + j][lr] = vu[j];
    }
    __syncthreads();
    #pragma unroll
    for (int kk = 0; kk < BK; ++kk) {
      float xv[4], gv[4], uv[4];
      *(float4*)xv = *(const float4*)&xs[kk][ty * 4];
      *(float4*)gv = *(const float4*)&gs[kk][tx * 4];
      *(float4*)uv = *(const float4*)&us[kk][tx * 4];
      #pragma unroll
      for (int i = 0; i < 4; ++i)
        #pragma unroll
        for (int j = 0; j < 4; ++j) {
          accg[i][j] = fmaf(xv[i], gv[j], accg[i][j]);
          accu[i][j] = fmaf(xv[i], uv[j], accu[i][j]);
        }
    }
  }

  #pragma unroll
  for (int i = 0; i < 4; ++i) {
    int r = ty * 4 + i;
    int en = ent[r];
    if (en < 0) continue;
    float w = rw[r];
    float* mrow = mixed + (size_t)en * M_DIM + m0 + tx * 4;
    float4 o;
    float g0 = accg[i][0], g1 = accg[i][1], g2 = accg[i][2], g3 = accg[i][3];
    o.x = (g0 / (1.f + expf(-g0))) * accu[i][0] * w;
    o.y = (g1 / (1.f + expf(-g1))) * accu[i][1] * w;
    o.z = (g2 / (1.f + expf(-g2))) * accu[i][2] * w;
    o.w = (g3 / (1.f + expf(-g3))) * accu[i][3] * w;
    *(float4*)mrow = o;
  }
}

// ---------------- K4: per-expert down GEMM, atomic accumulate into out -------
__global__ __launch_bounds__(256) void down_kernel(
    const float* __restrict__ w_down, const float* __restrict__ mixed,
    const int* __restrict__ cursors, const int* __restrict__ tok_list,
    float* __restrict__ out) {
  int e = blockIdx.z;
  int tile = blockIdx.x;
  int cnt = cursors[e];
  if (tile * BT >= cnt) return;
  int h0 = blockIdx.y * BH;

  __shared__ float ms[BK][BT];
  __shared__ float ds_[BK][BH];
  __shared__ int   ent[BT];

  int tid = threadIdx.x;
  if (tid < BT) {
    int idx = tile * BT + tid;
    ent[tid] = (idx < cnt) ? tok_list[e * T_TOK + idx] : -1;
  }
  __syncthreads();

  const float* wd = w_down + (size_t)e * H_DIM * M_DIM;
  int lr = tid >> 2;
  int lc = (tid & 3) * 8;
  int en_r = ent[lr];
  bool valid_r = (en_r >= 0);
  const float* mrow = mixed + (size_t)(valid_r ? en_r : 0) * M_DIM;
  const float* wrow = wd + (size_t)(h0 + lr) * M_DIM;

  int tx = tid & 15, ty = tid >> 4;
  float acc[4][4] = {{0}};

  for (int k0 = 0; k0 < M_DIM; k0 += BK) {
    float vm[8], vw[8];
    if (valid_r) {
      *(float4*)(vm)     = *(const float4*)(mrow + k0 + lc);
      *(float4*)(vm + 4) = *(const float4*)(mrow + k0 + lc + 4);
    } else {
      #pragma unroll
      for (int j = 0; j < 8; ++j) vm[j] = 0.f;
    }
    *(float4*)(vw)     = *(const float4*)(wrow + k0 + lc);
    *(float4*)(vw + 4) = *(const float4*)(wrow + k0 + lc + 4);
    __syncthreads();
    #pragma unroll
    for (int j = 0; j < 8; ++j) {
      ms[lc + j][lr]  = vm[j];
      ds_[lc + j][lr] = vw[j];
    }
    __syncthreads();
    #pragma unroll
    for (int kk = 0; kk < BK; ++kk) {
      float mv[4], wv[4];
      *(float4*)mv = *(const float4*)&ms[kk][ty * 4];
      *(float4*)wv = *(const float4*)&ds_[kk][tx * 4];
      #pragma unroll
      for (int i = 0; i < 4; ++i)
        #pragma unroll
        for (int j = 0; j < 4; ++j)
          acc[i][j] = fmaf(mv[i], wv[j], acc[i][j]);
    }
  }

  #pragma unroll
  for (int i = 0; i < 4; ++i) {
    int r = ty * 4 + i;
    int en = ent[r];
    if (en < 0) continue;
    int t = en >> 2;
    float* orow = out + (size_t)t * H_DIM + h0 + tx * 4;
    #pragma unroll
    for (int j = 0; j < 4; ++j) atomicAdd(orow + j, acc[i][j]);
  }
}

extern "C" void kernel_launch(void* const* d_in, const int* in_sizes, int n_in,
                              void* d_out, int out_size, void* d_ws, size_t ws_size,
                              hipStream_t stream) {
  const float* x      = (const float*)d_in[0];
  const float* gate_w = (const float*)d_in[1];
  const float* w_gate = (const float*)d_in[2];
  const float* w_up   = (const float*)d_in[3];
  const float* w_down = (const float*)d_in[4];
  float* out = (float*)d_out;

  char* ws = (char*)d_ws;
  size_t off = 0;
  int*   topk_ids = (int*)(ws + off);   off += (size_t)T_TOK * TOPK * 4;
  float* topk_w   = (float*)(ws + off); off += (size_t)T_TOK * TOPK * 4;
  int*   cursors  = (int*)(ws + off);   off += 256;  // E_NUM ints, padded
  int*   tok_list = (int*)(ws + off);   off += (size_t)E_NUM * T_TOK * 4;
  float* mixed    = (float*)(ws + off); off += (size_t)T_TOK * TOPK * M_DIM * 4;

  hipMemsetAsync(cursors, 0, E_NUM * sizeof(int), stream);
  hipMemsetAsync(out, 0, (size_t)T_TOK * H_DIM * sizeof(float), stream);

  gating_kernel<<<T_TOK, 256, 0, stream>>>(x, gate_w, topk_ids, topk_w);
  scatter_kernel<<<(T_TOK * TOPK) / 256, 256, 0, stream>>>(topk_ids, cursors, tok_list);
  gateup_kernel<<<dim3(T_TOK / BT, M_DIM / BM, E_NUM), 256, 0, stream>>>(
      x, w_gate, w_up, topk_w, cursors, tok_list, mixed);
  down_kernel<<<dim3(T_TOK / BT, H_DIM / BH, E_NUM), 256, 0, stream>>>(
      w_down, mixed, cursors, tok_list, out);
}

// Round 2
// 228.810 us; speedup vs baseline: 9.3819x; 9.3819x over previous
//
#include <hip/hip_runtime.h>
#include <math.h>

#define T_TOK 2048
#define H_DIM 1024
#define M_DIM 512
#define E_NUM 32
#define TOPK  4

#define BT  64
#define BK  32
#define BKP 40   // LDS k-stride in ushorts: 80B rows, 16B-aligned
#define BM  64
#define BH  64
#define MAX_TILES 160  // proven bound: sum ceil(cnt_e/64) <= 159

typedef __bf16 bf16x8 __attribute__((ext_vector_type(8)));
typedef float f32x4 __attribute__((ext_vector_type(4)));
typedef unsigned short u16x8 __attribute__((ext_vector_type(8)));

__device__ __forceinline__ unsigned short f2bf(float f) {
  unsigned u = __float_as_uint(f);
  unsigned r = (u + 0x7fffu + ((u >> 16) & 1u)) >> 16;
  return (unsigned short)r;
}
__device__ __forceinline__ float bf2f(unsigned short h) {
  return __uint_as_float(((unsigned)h) << 16);
}
__device__ __forceinline__ void split8(const float* v, u16x8* hv, u16x8* lv) {
  #pragma unroll
  for (int j = 0; j < 8; ++j) {
    unsigned short h = f2bf(v[j]);
    (*hv)[j] = h;
    (*lv)[j] = f2bf(v[j] - bf2f(h));
  }
}
__device__ __forceinline__ f32x4 mfma16(bf16x8 a, bf16x8 b, f32x4 c) {
  return __builtin_amdgcn_mfma_f32_16x16x32_bf16(a, b, c, 0, 0, 0);
}

// ---------------- K1: gating (logits -> top4 -> softmax weights) -------------
__global__ __launch_bounds__(256) void gating_kernel(
    const float* __restrict__ x, const float* __restrict__ gate_w,
    int* __restrict__ topk_ids, float* __restrict__ topk_w) {
  __shared__ float xr[H_DIM];
  __shared__ float logits[E_NUM];
  int t = blockIdx.x;
  int tid = threadIdx.x;
  const float* xrow = x + (size_t)t * H_DIM;
  *(float4*)(xr + tid * 4) = *(const float4*)(xrow + tid * 4);
  __syncthreads();
  int wave = tid >> 6, lane = tid & 63;
  const float4* x4 = (const float4*)xr;
  for (int e8 = 0; e8 < 8; ++e8) {
    int e = wave * 8 + e8;
    const float4* g4 = (const float4*)(gate_w + (size_t)e * H_DIM);
    float p = 0.f;
    #pragma unroll
    for (int i = 0; i < 4; ++i) {
      float4 a = x4[lane + i * 64];
      float4 b = g4[lane + i * 64];
      p += a.x * b.x + a.y * b.y + a.z * b.z + a.w * b.w;
    }
    for (int off = 32; off > 0; off >>= 1) p += __shfl_down(p, off, 64);
    if (lane == 0) logits[e] = p;
  }
  __syncthreads();
  if (tid == 0) {
    float v[E_NUM];
    for (int e = 0; e < E_NUM; ++e) v[e] = logits[e];
    int ids[TOPK]; float vals[TOPK];
    for (int k = 0; k < TOPK; ++k) {
      int bi = 0; float bv = -1e30f;
      for (int e = 0; e < E_NUM; ++e) if (v[e] > bv) { bv = v[e]; bi = e; }
      ids[k] = bi; vals[k] = bv; v[bi] = -1e30f;
    }
    float m = vals[0];
    float w[TOPK]; float s = 0.f;
    for (int k = 0; k < TOPK; ++k) { w[k] = expf(vals[k] - m); s += w[k]; }
    float inv = 1.f / s;
    for (int k = 0; k < TOPK; ++k) {
      topk_ids[t * TOPK + k] = ids[k];
      topk_w[t * TOPK + k]   = w[k] * inv;
    }
  }
}

// ---------------- K2: scatter assignments into per-expert lists --------------
__global__ __launch_bounds__(256) void scatter_kernel(
    const int* __restrict__ topk_ids, int* __restrict__ cursors,
    int* __restrict__ tok_list) {
  int g = blockIdx.x * 256 + threadIdx.x;
  if (g >= T_TOK * TOPK) return;
  int e = topk_ids[g];
  int slot = atomicAdd(&cursors[e], 1);
  tok_list[e * T_TOK + slot] = g;
}

// ---------------- K2b: build compact tile work list --------------------------
__global__ void build_tiles(const int* __restrict__ cursors,
                            int* __restrict__ n_tiles, int* __restrict__ tile_list) {
  int lane = threadIdx.x;  // 64 threads
  int nt = 0;
  if (lane < E_NUM) nt = (cursors[lane] + BT - 1) / BT;
  int pfx = nt;
  for (int off = 1; off < 64; off <<= 1) {
    int v = __shfl_up(pfx, off, 64);
    if (lane >= off) pfx += v;
  }
  int excl = pfx - nt;
  if (lane == E_NUM - 1) *n_tiles = pfx;
  if (lane < E_NUM)
    for (int i = 0; i < nt; ++i) tile_list[excl + i] = (lane << 8) | i;
}

// ---------------- K3: per-expert gate/up MFMA + silu*up*routew -> mixed ------
__global__ __launch_bounds__(256) void gateup_mfma(
    const float* __restrict__ x, const float* __restrict__ w_gate,
    const float* __restrict__ w_up, const float* __restrict__ topk_w,
    const int* __restrict__ cursors, const int* __restrict__ tok_list,
    const int* __restrict__ n_tiles, const int* __restrict__ tile_list,
    float* __restrict__ mixed) {
  int tid = threadIdx.x;
  if (blockIdx.x >= *n_tiles) return;
  int entry = tile_list[blockIdx.x];
  int e = entry >> 8, tile = entry & 255;
  int cnt = cursors[e];
  int m0 = blockIdx.y * BM;

  __shared__ unsigned short Ah[BT][BKP], Al[BT][BKP];
  __shared__ unsigned short Gh[BM][BKP], Gl[BM][BKP];
  __shared__ unsigned short Uh[BM][BKP], Ul[BM][BKP];
  __shared__ int   ent[BT];
  __shared__ float rw[BT];

  if (tid < BT) {
    int idx = tile * BT + tid;
    int en = (idx < cnt) ? tok_list[e * T_TOK + idx] : -1;
    ent[tid] = en;
    rw[tid]  = (en >= 0) ? topk_w[en] : 0.f;
  }
  __syncthreads();

  int srow = tid >> 2, quad = tid & 3;
  int kbase = quad * 8;
  int enr = ent[srow];
  bool aval = enr >= 0;
  const float* pA = x + (size_t)(aval ? (enr >> 2) : 0) * H_DIM + kbase;
  const float* pG = w_gate + ((size_t)e * M_DIM + m0 + srow) * H_DIM + kbase;
  const float* pU = w_up   + ((size_t)e * M_DIM + m0 + srow) * H_DIM + kbase;

  int lane = tid & 63, wid = tid >> 6;
  int wr = (wid >> 1) * 32, wc = (wid & 1) * 32;
  int r16 = lane & 15, koff = (lane >> 4) * 8;

  f32x4 accg[2][2] = {}; f32x4 accu[2][2] = {};

  const float4 z4 = make_float4(0.f, 0.f, 0.f, 0.f);
  float4 ra0, ra1, rg0, rg1, ru0, ru1;
  ra0 = aval ? *(const float4*)(pA)     : z4;
  ra1 = aval ? *(const float4*)(pA + 4) : z4;
  rg0 = *(const float4*)(pG); rg1 = *(const float4*)(pG + 4);
  ru0 = *(const float4*)(pU); ru1 = *(const float4*)(pU + 4);

  const int NK = H_DIM / BK;
  for (int ks = 0; ks < NK; ++ks) {
    __syncthreads();
    {
      float t8[8]; u16x8 hv, lv;
      *(float4*)t8 = ra0; *(float4*)(t8 + 4) = ra1;
      split8(t8, &hv, &lv);
      *(u16x8*)&Ah[srow][kbase] = hv; *(u16x8*)&Al[srow][kbase] = lv;
      *(float4*)t8 = rg0; *(float4*)(t8 + 4) = rg1;
      split8(t8, &hv, &lv);
      *(u16x8*)&Gh[srow][kbase] = hv; *(u16x8*)&Gl[srow][kbase] = lv;
      *(float4*)t8 = ru0; *(float4*)(t8 + 4) = ru1;
      split8(t8, &hv, &lv);
      *(u16x8*)&Uh[srow][kbase] = hv; *(u16x8*)&Ul[srow][kbase] = lv;
    }
    __syncthreads();
    if (ks + 1 < NK) {
      int k0 = (ks + 1) * BK;
      ra0 = aval ? *(const float4*)(pA + k0)     : z4;
      ra1 = aval ? *(const float4*)(pA + k0 + 4) : z4;
      rg0 = *(const float4*)(pG + k0); rg1 = *(const float4*)(pG + k0 + 4);
      ru0 = *(const float4*)(pU + k0); ru1 = *(const float4*)(pU + k0 + 4);
    }
    bf16x8 ah0 = *(const bf16x8*)&Ah[wr + r16][koff];
    bf16x8 ah1 = *(const bf16x8*)&Ah[wr + 16 + r16][koff];
    bf16x8 al0 = *(const bf16x8*)&Al[wr + r16][koff];
    bf16x8 al1 = *(const bf16x8*)&Al[wr + 16 + r16][koff];
    #pragma unroll
    for (int nf = 0; nf < 2; ++nf) {
      int br = wc + nf * 16 + r16;
      bf16x8 gh = *(const bf16x8*)&Gh[br][koff];
      bf16x8 gl = *(const bf16x8*)&Gl[br][koff];
      bf16x8 uh = *(const bf16x8*)&Uh[br][koff];
      bf16x8 ul = *(const bf16x8*)&Ul[br][koff];
      accg[0][nf] = mfma16(ah0, gh, accg[0][nf]);
      accg[0][nf] = mfma16(ah0, gl, accg[0][nf]);
      accg[0][nf] = mfma16(al0, gh, accg[0][nf]);
      accg[1][nf] = mfma16(ah1, gh, accg[1][nf]);
      accg[1][nf] = mfma16(ah1, gl, accg[1][nf]);
      accg[1][nf] = mfma16(al1, gh, accg[1][nf]);
      accu[0][nf] = mfma16(ah0, uh, accu[0][nf]);
      accu[0][nf] = mfma16(ah0, ul, accu[0][nf]);
      accu[0][nf] = mfma16(al0, uh, accu[0][nf]);
      accu[1][nf] = mfma16(ah1, uh, accu[1][nf]);
      accu[1][nf] = mfma16(ah1, ul, accu[1][nf]);
      accu[1][nf] = mfma16(al1, uh, accu[1][nf]);
    }
  }

  #pragma unroll
  for (int mf = 0; mf < 2; ++mf) {
    #pragma unroll
    for (int j = 0; j < 4; ++j) {
      int tr = wr + mf * 16 + (lane >> 4) * 4 + j;
      int en = ent[tr];
      if (en < 0) continue;
      float w = rw[tr];
      #pragma unroll
      for (int nf = 0; nf < 2; ++nf) {
        float g = accg[mf][nf][j], u = accu[mf][nf][j];
        float val = (g / (1.f + __expf(-g))) * u * w;
        mixed[(size_t)en * M_DIM + m0 + wc + nf * 16 + (lane & 15)] = val;
      }
    }
  }
}

// ---------------- K4: per-expert down MFMA, atomic accumulate into out -------
__global__ __launch_bounds__(256) void down_mfma(
    const float* __restrict__ w_down, const float* __restrict__ mixed,
    const int* __restrict__ cursors, const int* __restrict__ tok_list,
    const int* __restrict__ n_tiles, const int* __restrict__ tile_list,
    float* __restrict__ out) {
  int tid = threadIdx.x;
  if (blockIdx.x >= *n_tiles) return;
  int entry = tile_list[blockIdx.x];
  int e = entry >> 8, tile = entry & 255;
  int cnt = cursors[e];
  int h0 = blockIdx.y * BH;

  __shared__ unsigned short Ah[BT][BKP], Al[BT][BKP];
  __shared__ unsigned short Dh[BH][BKP], Dl[BH][BKP];
  __shared__ int ent[BT];

  if (tid < BT) {
    int idx = tile * BT + tid;
    ent[tid] = (idx < cnt) ? tok_list[e * T_TOK + idx] : -1;
  }
  __syncthreads();

  int srow = tid >> 2, quad = tid & 3, kbase = quad * 8;
  int enr = ent[srow];
  bool aval = enr >= 0;
  const float* pA = mixed  + (size_t)(aval ? enr : 0) * M_DIM + kbase;
  const float* pD = w_down + ((size_t)e * H_DIM + h0 + srow) * M_DIM + kbase;

  int lane = tid & 63, wid = tid >> 6;
  int wr = (wid >> 1) * 32, wc = (wid & 1) * 32;
  int r16 = lane & 15, koff = (lane >> 4) * 8;

  f32x4 acc[2][2] = {};
  const float4 z4 = make_float4(0.f, 0.f, 0.f, 0.f);
  float4 ra0, ra1, rd0, rd1;
  ra0 = aval ? *(const float4*)(pA)     : z4;
  ra1 = aval ? *(const float4*)(pA + 4) : z4;
  rd0 = *(const float4*)(pD); rd1 = *(const float4*)(pD + 4);

  const int NK = M_DIM / BK;
  for (int ks = 0; ks < NK; ++ks) {
    __syncthreads();
    {
      float t8[8]; u16x8 hv, lv;
      *(float4*)t8 = ra0; *(float4*)(t8 + 4) = ra1;
      split8(t8, &hv, &lv);
      *(u16x8*)&Ah[srow][kbase] = hv; *(u16x8*)&Al[srow][kbase] = lv;
      *(float4*)t8 = rd0; *(float4*)(t8 + 4) = rd1;
      split8(t8, &hv, &lv);
      *(u16x8*)&Dh[srow][kbase] = hv; *(u16x8*)&Dl[srow][kbase] = lv;
    }
    __syncthreads();
    if (ks + 1 < NK) {
      int k0 = (ks + 1) * BK;
      ra0 = aval ? *(const float4*)(pA + k0)     : z4;
      ra1 = aval ? *(const float4*)(pA + k0 + 4) : z4;
      rd0 = *(const float4*)(pD + k0); rd1 = *(const float4*)(pD + k0 + 4);
    }
    bf16x8 ah0 = *(const bf16x8*)&Ah[wr + r16][koff];
    bf16x8 ah1 = *(const bf16x8*)&Ah[wr + 16 + r16][koff];
    bf16x8 al0 = *(const bf16x8*)&Al[wr + r16][koff];
    bf16x8 al1 = *(const bf16x8*)&Al[wr + 16 + r16][koff];
    #pragma unroll
    for (int nf = 0; nf < 2; ++nf) {
      int br = wc + nf * 16 + r16;
      bf16x8 dh = *(const bf16x8*)&Dh[br][koff];
      bf16x8 dl = *(const bf16x8*)&Dl[br][koff];
      acc[0][nf] = mfma16(ah0, dh, acc[0][nf]);
      acc[0][nf] = mfma16(ah0, dl, acc[0][nf]);
      acc[0][nf] = mfma16(al0, dh, acc[0][nf]);
      acc[1][nf] = mfma16(ah1, dh, acc[1][nf]);
      acc[1][nf] = mfma16(ah1, dl, acc[1][nf]);
      acc[1][nf] = mfma16(al1, dh, acc[1][nf]);
    }
  }

  #pragma unroll
  for (int mf = 0; mf < 2; ++mf) {
    #pragma unroll
    for (int j = 0; j < 4; ++j) {
      int tr = wr + mf * 16 + (lane >> 4) * 4 + j;
      int en = ent[tr];
      if (en < 0) continue;
      int t = en >> 2;
      #pragma unroll
      for (int nf = 0; nf < 2; ++nf)
        atomicAdd(&out[(size_t)t * H_DIM + h0 + wc + nf * 16 + (lane & 15)],
                  acc[mf][nf][j]);
    }
  }
}

extern "C" void kernel_launch(void* const* d_in, const int* in_sizes, int n_in,
                              void* d_out, int out_size, void* d_ws, size_t ws_size,
                              hipStream_t stream) {
  const float* x      = (const float*)d_in[0];
  const float* gate_w = (const float*)d_in[1];
  const float* w_gate = (const float*)d_in[2];
  const float* w_up   = (const float*)d_in[3];
  const float* w_down = (const float*)d_in[4];
  float* out = (float*)d_out;

  char* ws = (char*)d_ws;
  size_t off = 0;
  int*   topk_ids  = (int*)(ws + off);   off += (size_t)T_TOK * TOPK * 4;
  float* topk_w    = (float*)(ws + off); off += (size_t)T_TOK * TOPK * 4;
  int*   cursors   = (int*)(ws + off);   off += 256;
  int*   n_tiles   = (int*)(ws + off);   off += 64;
  int*   tile_list = (int*)(ws + off);   off += MAX_TILES * 4 + 64;
  int*   tok_list  = (int*)(ws + off);   off += (size_t)E_NUM * T_TOK * 4;
  float* mixed     = (float*)(ws + off); off += (size_t)T_TOK * TOPK * M_DIM * 4;

  hipMemsetAsync(cursors, 0, E_NUM * sizeof(int), stream);
  hipMemsetAsync(out, 0, (size_t)T_TOK * H_DIM * sizeof(float), stream);

  gating_kernel<<<T_TOK, 256, 0, stream>>>(x, gate_w, topk_ids, topk_w);
  scatter_kernel<<<(T_TOK * TOPK) / 256, 256, 0, stream>>>(topk_ids, cursors, tok_list);
  build_tiles<<<1, 64, 0, stream>>>(cursors, n_tiles, tile_list);
  gateup_mfma<<<dim3(MAX_TILES, M_DIM / BM), 256, 0, stream>>>(
      x, w_gate, w_up, topk_w, cursors, tok_list, n_tiles, tile_list, mixed);
  down_mfma<<<dim3(MAX_TILES, H_DIM / BH), 256, 0, stream>>>(
      w_down, mixed, cursors, tok_list, n_tiles, tile_list, out);
}

// Round 3
// 163.116 us; speedup vs baseline: 13.1604x; 1.4027x over previous
//
#include <hip/hip_runtime.h>
#include <math.h>

#define T_TOK 2048
#define H_DIM 1024
#define M_DIM 512
#define E_NUM 32
#define TOPK  4

#define BT  128        // tokens per tile
#define BK  32         // k per step
#define GU_BM 64       // gateup N-tile
#define DN_BH 128      // down N-tile
#define MAX_TILES 96   // sum ceil(cnt_e/128) <= 32 + 8192/128 = 96

typedef __bf16 bf16x8 __attribute__((ext_vector_type(8)));
typedef float f32x4 __attribute__((ext_vector_type(4)));
typedef unsigned short u16x8 __attribute__((ext_vector_type(8)));

__device__ __forceinline__ unsigned short f2bf(float f) {
  unsigned u = __float_as_uint(f);
  return (unsigned short)((u + 0x7fffu + ((u >> 16) & 1u)) >> 16);
}
__device__ __forceinline__ float bf2f(unsigned short h) {
  return __uint_as_float(((unsigned)h) << 16);
}
__device__ __forceinline__ f32x4 mfma16(bf16x8 a, bf16x8 b, f32x4 c) {
  return __builtin_amdgcn_mfma_f32_16x16x32_bf16(a, b, c, 0, 0, 0);
}

// ---------------- split x into hi/lo bf16 ------------------------------------
__global__ __launch_bounds__(512) void split_x_kernel(
    const float* __restrict__ x, unsigned short* __restrict__ xh,
    unsigned short* __restrict__ xl) {
  int i = (blockIdx.x * 512 + threadIdx.x) * 8;
  float t8[8];
  *(float4*)t8 = *(const float4*)(x + i);
  *(float4*)(t8 + 4) = *(const float4*)(x + i + 4);
  u16x8 hv, lv;
  #pragma unroll
  for (int j = 0; j < 8; ++j) {
    unsigned short h = f2bf(t8[j]);
    hv[j] = h;
    lv[j] = f2bf(t8[j] - bf2f(h));
  }
  *(u16x8*)(xh + i) = hv;
  *(u16x8*)(xl + i) = lv;
}

// ---------------- K1: gating -------------------------------------------------
__global__ __launch_bounds__(256) void gating_kernel(
    const float* __restrict__ x, const float* __restrict__ gate_w,
    int* __restrict__ topk_ids, float* __restrict__ topk_w) {
  __shared__ float xr[H_DIM];
  __shared__ float logits[E_NUM];
  int t = blockIdx.x;
  int tid = threadIdx.x;
  const float* xrow = x + (size_t)t * H_DIM;
  *(float4*)(xr + tid * 4) = *(const float4*)(xrow + tid * 4);
  __syncthreads();
  int wave = tid >> 6, lane = tid & 63;
  const float4* x4 = (const float4*)xr;
  for (int e8 = 0; e8 < 8; ++e8) {
    int e = wave * 8 + e8;
    const float4* g4 = (const float4*)(gate_w + (size_t)e * H_DIM);
    float p = 0.f;
    #pragma unroll
    for (int i = 0; i < 4; ++i) {
      float4 a = x4[lane + i * 64];
      float4 b = g4[lane + i * 64];
      p += a.x * b.x + a.y * b.y + a.z * b.z + a.w * b.w;
    }
    for (int off = 32; off > 0; off >>= 1) p += __shfl_down(p, off, 64);
    if (lane == 0) logits[e] = p;
  }
  __syncthreads();
  if (tid == 0) {
    float v[E_NUM];
    for (int e = 0; e < E_NUM; ++e) v[e] = logits[e];
    int ids[TOPK]; float vals[TOPK];
    for (int k = 0; k < TOPK; ++k) {
      int bi = 0; float bv = -1e30f;
      for (int e = 0; e < E_NUM; ++e) if (v[e] > bv) { bv = v[e]; bi = e; }
      ids[k] = bi; vals[k] = bv; v[bi] = -1e30f;
    }
    float m = vals[0];
    float w[TOPK]; float s = 0.f;
    for (int k = 0; k < TOPK; ++k) { w[k] = expf(vals[k] - m); s += w[k]; }
    float inv = 1.f / s;
    for (int k = 0; k < TOPK; ++k) {
      topk_ids[t * TOPK + k] = ids[k];
      topk_w[t * TOPK + k]   = w[k] * inv;
    }
  }
}

// ---------------- K2: scatter ------------------------------------------------
__global__ __launch_bounds__(256) void scatter_kernel(
    const int* __restrict__ topk_ids, int* __restrict__ cursors,
    int* __restrict__ tok_list) {
  int g = blockIdx.x * 256 + threadIdx.x;
  if (g >= T_TOK * TOPK) return;
  int e = topk_ids[g];
  int slot = atomicAdd(&cursors[e], 1);
  tok_list[e * T_TOK + slot] = g;
}

// ---------------- K2b: tile work list ----------------------------------------
__global__ void build_tiles(const int* __restrict__ cursors,
                            int* __restrict__ n_tiles, int* __restrict__ tile_list) {
  int lane = threadIdx.x;
  int nt = 0;
  if (lane < E_NUM) nt = (cursors[lane] + BT - 1) / BT;
  int pfx = nt;
  for (int off = 1; off < 64; off <<= 1) {
    int v = __shfl_up(pfx, off, 64);
    if (lane >= off) pfx += v;
  }
  int excl = pfx - nt;
  if (lane == E_NUM - 1) *n_tiles = pfx;
  if (lane < E_NUM)
    for (int i = 0; i < nt; ++i) tile_list[excl + i] = (lane << 8) | i;
}

// ---------------- K3: gateup (A=x split hi/lo, B=weights bf16, 2-product) ----
// LDS fragment-contiguous layout: elem(row,k) at ushort off
//   (row>>4)*512 + (k>>3)*128 + (row&15)*8 + (k&7)
// -> wave frag read = base + lane*8 ushorts (linear, conflict-free)
__global__ __launch_bounds__(512) void gateup_mfma(
    const unsigned short* __restrict__ xh, const unsigned short* __restrict__ xl,
    const float* __restrict__ w_gate, const float* __restrict__ w_up,
    const float* __restrict__ topk_w,
    const int* __restrict__ cursors, const int* __restrict__ tok_list,
    const int* __restrict__ n_tiles, const int* __restrict__ tile_list,
    unsigned short* __restrict__ mixed) {
  if (blockIdx.y >= *n_tiles) return;
  int tid = threadIdx.x;
  int entry = tile_list[blockIdx.y];
  int e = entry >> 8, tile = entry & 255;
  int cnt = cursors[e];
  int m0 = blockIdx.x * GU_BM;

  __shared__ unsigned short Ah[BT * BK], Al[BT * BK];       // 8 KB each
  __shared__ unsigned short Gh[GU_BM * BK], Uh[GU_BM * BK]; // 4 KB each
  __shared__ int   ent[BT];
  __shared__ float rw[BT];

  if (tid < BT) {
    int idx = tile * BT + tid;
    int en = (idx < cnt) ? tok_list[e * T_TOK + idx] : -1;
    ent[tid] = en;
    rw[tid]  = (en >= 0) ? topk_w[en] : 0.f;
  }
  __syncthreads();

  // A staging: 512 threads cover 128 rows x 4 k-octets
  int arow = tid >> 2, akq = tid & 3;
  int aen = ent[arow];
  if (aen < 0) aen = ent[0];  // garbage rows harmless: their out rows skipped
  const unsigned short* pAh = xh + (size_t)(aen >> 2) * H_DIM + akq * 8;
  const unsigned short* pAl = xl + (size_t)(aen >> 2) * H_DIM + akq * 8;
  int aoff = (arow >> 4) * 512 + akq * 128 + (arow & 15) * 8;

  // B staging: threads 0..255 -> G, 256..511 -> U (64 rows x 4 k-octets each)
  int bslot = tid & 255;
  int brow = bslot >> 2, bkq = bslot & 3;
  const float* pB = ((tid < 256) ? w_gate : w_up) +
                    ((size_t)e * M_DIM + m0 + brow) * H_DIM + bkq * 8;
  unsigned short* Bdst = (tid < 256) ? Gh : Uh;
  int boff = (brow >> 4) * 512 + bkq * 128 + (brow & 15) * 8;

  int lane = tid & 63, wid = tid >> 6;
  int wr = (wid >> 1) * 32;  // 0,32,64,96
  int wc = (wid & 1) * 32;   // 0,32
  int l16 = lane * 8;

  f32x4 accg[2][2] = {}; f32x4 accu[2][2] = {};

  u16x8 rah, ral; float bf8[8];
  rah = *(const u16x8*)pAh;
  ral = *(const u16x8*)pAl;
  *(float4*)bf8 = *(const float4*)pB;
  *(float4*)(bf8 + 4) = *(const float4*)(pB + 4);

  const int NK = H_DIM / BK;
  for (int ks = 0; ks < NK; ++ks) {
    u16x8 bh;
    #pragma unroll
    for (int j = 0; j < 8; ++j) bh[j] = f2bf(bf8[j]);
    __syncthreads();
    *(u16x8*)&Ah[aoff] = rah;
    *(u16x8*)&Al[aoff] = ral;
    *(u16x8*)&Bdst[boff] = bh;
    __syncthreads();
    if (ks + 1 < NK) {
      int kq = (ks + 1) * BK;
      rah = *(const u16x8*)(pAh + kq);
      ral = *(const u16x8*)(pAl + kq);
      *(float4*)bf8 = *(const float4*)(pB + kq);
      *(float4*)(bf8 + 4) = *(const float4*)(pB + kq + 4);
    }
    int ab = (wr >> 4) * 512 + l16;
    bf16x8 a0h = *(const bf16x8*)&Ah[ab];
    bf16x8 a1h = *(const bf16x8*)&Ah[ab + 512];
    bf16x8 a0l = *(const bf16x8*)&Al[ab];
    bf16x8 a1l = *(const bf16x8*)&Al[ab + 512];
    #pragma unroll
    for (int nf = 0; nf < 2; ++nf) {
      int nb = ((wc >> 4) + nf) * 512 + l16;
      bf16x8 g = *(const bf16x8*)&Gh[nb];
      bf16x8 u = *(const bf16x8*)&Uh[nb];
      accg[0][nf] = mfma16(a0h, g, accg[0][nf]);
      accg[0][nf] = mfma16(a0l, g, accg[0][nf]);
      accg[1][nf] = mfma16(a1h, g, accg[1][nf]);
      accg[1][nf] = mfma16(a1l, g, accg[1][nf]);
      accu[0][nf] = mfma16(a0h, u, accu[0][nf]);
      accu[0][nf] = mfma16(a0l, u, accu[0][nf]);
      accu[1][nf] = mfma16(a1h, u, accu[1][nf]);
      accu[1][nf] = mfma16(a1l, u, accu[1][nf]);
    }
  }

  #pragma unroll
  for (int mf = 0; mf < 2; ++mf) {
    #pragma unroll
    for (int j = 0; j < 4; ++j) {
      int tr = wr + mf * 16 + (lane >> 4) * 4 + j;
      int en = ent[tr];
      if (en < 0) continue;
      float w = rw[tr];
      #pragma unroll
      for (int nf = 0; nf < 2; ++nf) {
        float g = accg[mf][nf][j], u = accu[mf][nf][j];
        float val = (g / (1.f + __expf(-g))) * u * w;
        mixed[(size_t)en * M_DIM + m0 + wc + nf * 16 + (lane & 15)] = f2bf(val);
      }
    }
  }
}

// ---------------- K4: down (pure bf16, 1-product) ----------------------------
__global__ __launch_bounds__(512) void down_mfma(
    const float* __restrict__ w_down, const unsigned short* __restrict__ mixed,
    const int* __restrict__ cursors, const int* __restrict__ tok_list,
    const int* __restrict__ n_tiles, const int* __restrict__ tile_list,
    float* __restrict__ out) {
  if (blockIdx.y >= *n_tiles) return;
  int tid = threadIdx.x;
  int entry = tile_list[blockIdx.y];
  int e = entry >> 8, tile = entry & 255;
  int cnt = cursors[e];
  int h0 = blockIdx.x * DN_BH;

  __shared__ unsigned short As[BT * BK];      // 8 KB
  __shared__ unsigned short Bs[DN_BH * BK];   // 8 KB
  __shared__ int ent[BT];

  if (tid < BT) {
    int idx = tile * BT + tid;
    ent[tid] = (idx < cnt) ? tok_list[e * T_TOK + idx] : -1;
  }
  __syncthreads();

  int arow = tid >> 2, akq = tid & 3;
  int aen = ent[arow];
  if (aen < 0) aen = ent[0];
  const unsigned short* pA = mixed + (size_t)aen * M_DIM + akq * 8;
  int aoff = (arow >> 4) * 512 + akq * 128 + (arow & 15) * 8;

  const float* pB = w_down + ((size_t)e * H_DIM + h0 + arow) * M_DIM + akq * 8;

  int lane = tid & 63, wid = tid >> 6;
  int wr = (wid >> 1) * 32, wc = (wid & 1) * 64;
  int l16 = lane * 8;

  f32x4 acc[2][4] = {};
  u16x8 ra; float bf8[8];
  ra = *(const u16x8*)pA;
  *(float4*)bf8 = *(const float4*)pB;
  *(float4*)(bf8 + 4) = *(const float4*)(pB + 4);

  const int NK = M_DIM / BK;
  for (int ks = 0; ks < NK; ++ks) {
    u16x8 bh;
    #pragma unroll
    for (int j = 0; j < 8; ++j) bh[j] = f2bf(bf8[j]);
    __syncthreads();
    *(u16x8*)&As[aoff] = ra;
    *(u16x8*)&Bs[aoff] = bh;
    __syncthreads();
    if (ks + 1 < NK) {
      int kq = (ks + 1) * BK;
      ra = *(const u16x8*)(pA + kq);
      *(float4*)bf8 = *(const float4*)(pB + kq);
      *(float4*)(bf8 + 4) = *(const float4*)(pB + kq + 4);
    }
    int ab = (wr >> 4) * 512 + l16;
    bf16x8 a0 = *(const bf16x8*)&As[ab];
    bf16x8 a1 = *(const bf16x8*)&As[ab + 512];
    #pragma unroll
    for (int nf = 0; nf < 4; ++nf) {
      bf16x8 b = *(const bf16x8*)&Bs[((wc >> 4) + nf) * 512 + l16];
      acc[0][nf] = mfma16(a0, b, acc[0][nf]);
      acc[1][nf] = mfma16(a1, b, acc[1][nf]);
    }
  }

  #pragma unroll
  for (int mf = 0; mf < 2; ++mf) {
    #pragma unroll
    for (int j = 0; j < 4; ++j) {
      int tr = wr + mf * 16 + (lane >> 4) * 4 + j;
      int en = ent[tr];
      if (en < 0) continue;
      int t = en >> 2;
      #pragma unroll
      for (int nf = 0; nf < 4; ++nf)
        atomicAdd(&out[(size_t)t * H_DIM + h0 + wc + nf * 16 + (lane & 15)],
                  acc[mf][nf][j]);
    }
  }
}

extern "C" void kernel_launch(void* const* d_in, const int* in_sizes, int n_in,
                              void* d_out, int out_size, void* d_ws, size_t ws_size,
                              hipStream_t stream) {
  const float* x      = (const float*)d_in[0];
  const float* gate_w = (const float*)d_in[1];
  const float* w_gate = (const float*)d_in[2];
  const float* w_up   = (const float*)d_in[3];
  const float* w_down = (const float*)d_in[4];
  float* out = (float*)d_out;

  char* ws = (char*)d_ws;
  size_t off = 0;
  int*   topk_ids  = (int*)(ws + off);   off += (size_t)T_TOK * TOPK * 4;
  float* topk_w    = (float*)(ws + off); off += (size_t)T_TOK * TOPK * 4;
  int*   cursors   = (int*)(ws + off);   off += 256;
  int*   n_tiles   = (int*)(ws + off);   off += 64;
  int*   tile_list = (int*)(ws + off);   off += MAX_TILES * 4 + 64;
  int*   tok_list  = (int*)(ws + off);   off += (size_t)E_NUM * T_TOK * 4;
  unsigned short* x_hi  = (unsigned short*)(ws + off); off += (size_t)T_TOK * H_DIM * 2;
  unsigned short* x_lo  = (unsigned short*)(ws + off); off += (size_t)T_TOK * H_DIM * 2;
  unsigned short* mixed = (unsigned short*)(ws + off); off += (size_t)T_TOK * TOPK * M_DIM * 2;

  hipMemsetAsync(cursors, 0, E_NUM * sizeof(int), stream);
  hipMemsetAsync(out, 0, (size_t)T_TOK * H_DIM * sizeof(float), stream);

  split_x_kernel<<<T_TOK * H_DIM / (512 * 8), 512, 0, stream>>>(x, x_hi, x_lo);
  gating_kernel<<<T_TOK, 256, 0, stream>>>(x, gate_w, topk_ids, topk_w);
  scatter_kernel<<<(T_TOK * TOPK) / 256, 256, 0, stream>>>(topk_ids, cursors, tok_list);
  build_tiles<<<1, 64, 0, stream>>>(cursors, n_tiles, tile_list);
  gateup_mfma<<<dim3(M_DIM / GU_BM, MAX_TILES), 512, 0, stream>>>(
      x_hi, x_lo, w_gate, w_up, topk_w, cursors, tok_list, n_tiles, tile_list, mixed);
  down_mfma<<<dim3(H_DIM / DN_BH, MAX_TILES), 512, 0, stream>>>(
      w_down, mixed, cursors, tok_list, n_tiles, tile_list, out);
}